// Round 3
// baseline (409.662 us; speedup 1.0000x reference)
//
#include <hip/hip_runtime.h>
#include <math.h>

#define B 8
#define V 1024
#define E 32
#define F 64
#define H 4
#define HIDN 64
#define CAP 64        // max out-degree capacity; E[deg]=17, P(deg>64) ~ 1e-21
#define MAXNNZ 20480  // nnz ~ 17390 +/- 128; +24 sigma headroom

__device__ __forceinline__ float wave_sum(float v) {
  for (int o = 32; o > 0; o >>= 1) v += __shfl_xor(v, o);
  return v;
}
__device__ __forceinline__ float wave_max(float v) {
  for (int o = 32; o > 0; o >>= 1) v = fmaxf(v, __shfl_xor(v, o));
  return v;
}

// ---- adjacency -> CSR out-neighbor lists (row-coalesced ballot compaction) ----
__global__ void build_csr(const float* __restrict__ adj, int* __restrict__ nbr,
                          int* __restrict__ deg) {
  int v = blockIdx.x;
  int lane = threadIdx.x;
  int base = 0;
  for (int c = 0; c < V; c += 64) {
    float a = adj[v * V + c + lane];
    unsigned long long m = __ballot(a > 0.5f);
    int pos = __popcll(m & ((1ull << lane) - 1ull));
    if (a > 0.5f && base + pos < CAP) nbr[v * CAP + base + pos] = c + lane;
    base += __popcll(m);
  }
  if (lane == 0) deg[v] = (base < CAP) ? base : CAP;
}

// ---- in-degree per column, row-coalesced ----
__global__ __launch_bounds__(1024) void colcount_kernel(const float* __restrict__ adj,
                                                        int* __restrict__ deg_in) {
  __shared__ int part[16][64];
  int w0 = blockIdx.x * 64;
  int t = threadIdx.x;
  int wave = t >> 6, lane = t & 63;
  int col = w0 + lane;
  int cnt = 0;
  for (int r = wave; r < V; r += 16) cnt += (adj[(size_t)r * V + col] > 0.5f) ? 1 : 0;
  part[wave][lane] = cnt;
  __syncthreads();
  if (t < 64) {
    int s = 0;
#pragma unroll
    for (int i = 0; i < 16; ++i) s += part[i][t];
    deg_in[w0 + t] = s;
  }
}

// ---- exclusive prefix scan of deg_in -> in_off[V+1], single block ----
__global__ void scan_kernel(const int* __restrict__ deg_in, int* __restrict__ in_off) {
  __shared__ int s[V];
  int v = threadIdx.x;
  int d = deg_in[v];
  s[v] = d;
  __syncthreads();
  for (int o = 1; o < V; o <<= 1) {
    int t = (v >= o) ? s[v - o] : 0;
    __syncthreads();
    s[v] += t;
    __syncthreads();
  }
  in_off[v] = s[v] - d;  // exclusive
  if (v == V - 1) in_off[V] = s[v];
}

// ---- CSC build via LDS tile transpose (adj read row-coalesced) ----
// c_src[idx] = source node of idx-th CSC edge; csc_pos[v*CAP+k] = CSC index of
// v's k-th out-edge (inverse map used by fw_kernel's direct scatter).
__global__ __launch_bounds__(1024) void build_csc2(const float* __restrict__ adj,
                                                   const int* __restrict__ nbr_out,
                                                   const int* __restrict__ deg_out,
                                                   const int* __restrict__ in_off,
                                                   unsigned short* __restrict__ c_src,
                                                   int* __restrict__ csc_pos) {
  __shared__ float tile[64][65];
  __shared__ int cbase[64];
  int w0 = blockIdx.x * 64;
  int t = threadIdx.x;
  int wave = t >> 6, lane = t & 63;
  if (t < 64) cbase[t] = in_off[w0 + t];
  __syncthreads();
  for (int c = 0; c < 16; ++c) {
#pragma unroll
    for (int i = 0; i < 4; ++i) {
      int e = t + i * 1024;
      int r = e >> 6, col = e & 63;
      tile[r][col] = adj[(size_t)(c * 64 + r) * V + w0 + col];
    }
    __syncthreads();
#pragma unroll
    for (int cc = 0; cc < 4; ++cc) {
      int col = wave * 4 + cc;
      float a = tile[lane][col];
      unsigned long long m = __ballot(a > 0.5f);
      int pos = __popcll(m & ((1ull << lane) - 1ull));
      if (a > 0.5f) {
        int v = c * 64 + lane;
        int w = w0 + col;
        int idx = cbase[col] + pos;
        int dv_ = deg_out[v];
        int kk = 0;
        for (int k = 0; k < dv_; ++k)
          if (nbr_out[v * CAP + k] == w) { kk = k; break; }
        c_src[idx] = (unsigned short)v;
        csc_pos[v * CAP + kk] = idx;
      }
      if (lane == 0) cbase[col] += __popcll(m);
    }
    __syncthreads();
  }
}

// ---- encoder MLP, 8 nodes/block to amortize weight reads ----
#define ENV 8
__global__ void enc_kernel(const float* __restrict__ demands, const float* __restrict__ emb,
                           const float* __restrict__ w1, const float* __restrict__ b1,
                           const float* __restrict__ w2, const float* __restrict__ b2,
                           float* __restrict__ enc) {
  int bv0 = blockIdx.x * ENV;
  int b = bv0 >> 10, v0 = bv0 & 1023;
  int j = threadIdx.x;  // 64
  __shared__ float xs[ENV][E + 1];
  __shared__ float hs[ENV][64];
#pragma unroll
  for (int n = 0; n < ENV; ++n) {
    if (j < E) xs[n][j] = emb[(v0 + n) * E + j];
    else if (j == E) xs[n][E] = demands[b * V + v0 + n];
  }
  __syncthreads();
  float h[ENV];
#pragma unroll
  for (int n = 0; n < ENV; ++n) h[n] = b1[j];
  for (int i = 0; i < E + 1; ++i) {
    float wv = w1[i * 64 + j];
#pragma unroll
    for (int n = 0; n < ENV; ++n) h[n] += xs[n][i] * wv;
  }
#pragma unroll
  for (int n = 0; n < ENV; ++n) hs[n][j] = fmaxf(h[n], 0.f);
  __syncthreads();
  float o[ENV];
#pragma unroll
  for (int n = 0; n < ENV; ++n) o[n] = b2[j];
  for (int i = 0; i < 64; ++i) {
    float wv = w2[i * 64 + j];
#pragma unroll
    for (int n = 0; n < ENV; ++n) o[n] += hs[n][i] * wv;
  }
#pragma unroll
  for (int n = 0; n < ENV; ++n) enc[(bv0 + n) * 64 + j] = fmaxf(o[n], 0.f);
}

// ---- t = einsum('bvf,hfg->bhvg') + attention score projections, 8 nodes/block ----
#define TNV 8
__global__ void t_kernel(const float* __restrict__ enc, const float* __restrict__ gat_w,
                         const float* __restrict__ a1, const float* __restrict__ a2,
                         float* __restrict__ t, float* __restrict__ s_self,
                         float* __restrict__ s_nbr) {
  int bv0 = blockIdx.x * TNV;
  int b = bv0 >> 10, v0 = bv0 & 1023;
  int tid = threadIdx.x;  // 256
  int h = tid >> 6, g = tid & 63;
  __shared__ float es[TNV][64];
  for (int i = tid; i < TNV * 64; i += 256) es[i >> 6][i & 63] = enc[bv0 * 64 + i];
  __syncthreads();
  float acc[TNV];
#pragma unroll
  for (int n = 0; n < TNV; ++n) acc[n] = 0.f;
  const float* w = gat_w + h * 64 * 64 + g;
  for (int f = 0; f < 64; ++f) {
    float wf = w[f * 64];
#pragma unroll
    for (int n = 0; n < TNV; ++n) acc[n] += es[n][f] * wf;
  }
  float a1v = a1[h * 64 + g], a2v = a2[h * 64 + g];
#pragma unroll
  for (int n = 0; n < TNV; ++n) {
    t[((size_t)(b * H + h) * V + (v0 + n)) * 64 + g] = acc[n];
    float v1 = wave_sum(acc[n] * a1v);
    float v2 = wave_sum(acc[n] * a2v);
    if (g == 0) {
      s_self[(b * H + h) * V + (v0 + n)] = v1;
      s_nbr[(b * H + h) * V + (v0 + n)] = v2;
    }
  }
}

// ---- sparse GAT attention + head-mean + GRU-style gate ----
__global__ void gat_kernel(const float* __restrict__ enc_in, const float* __restrict__ t,
                           const float* __restrict__ s_self, const float* __restrict__ s_nbr,
                           const int* __restrict__ nbr, const int* __restrict__ deg,
                           const float* __restrict__ gate_w, const float* __restrict__ gate_u,
                           const float* __restrict__ gate_b, float* __restrict__ enc_out) {
  int bv = blockIdx.x;
  int b = bv >> 10, v = bv & 1023;
  int tid = threadIdx.x;
  int h = tid >> 6, lane = tid & 63;
  int dvv = deg[v];
  int wk = (lane < dvv) ? nbr[v * CAP + lane] : 0;
  float logit = -1e30f;
  if (lane < dvv) {
    float x = s_self[(b * H + h) * V + v] + s_nbr[(b * H + h) * V + wk];
    logit = (x > 0.f) ? x : 0.2f * x;  // leaky_relu 0.2
  }
  float m = wave_max(logit);
  float e = (lane < dvv) ? __expf(logit - m) : 0.f;
  float s = wave_sum(e);
  float coef = e / s;
  const float* tb = t + (size_t)(b * H + h) * (V * 64);
  float acc = 0.f;
  for (int k = 0; k < dvv; ++k) {
    float c = __shfl(coef, k);
    int w = __shfl(wk, k);
    acc += c * tb[w * 64 + lane];
  }
  __shared__ float hsum[4][64];
  __shared__ float nxts[64], encs[64];
  hsum[h][lane] = acc;
  __syncthreads();
  if (tid < 64) {
    float s4 = hsum[0][tid] + hsum[1][tid] + hsum[2][tid] + hsum[3][tid];
    nxts[tid] = fmaxf(0.25f * s4, 0.f);
    encs[tid] = enc_in[bv * 64 + tid];
  }
  __syncthreads();
  float part = 0.f;
  for (int f = h * 16; f < h * 16 + 16; ++f)
    part += nxts[f] * gate_w[f * 64 + lane] + encs[f] * gate_u[f * 64 + lane];
  __syncthreads();
  hsum[h][lane] = part;
  __syncthreads();
  if (tid < 64) {
    float zs = hsum[0][tid] + hsum[1][tid] + hsum[2][tid] + hsum[3][tid] + gate_b[tid];
    float z = 1.f / (1.f + __expf(-zs));
    enc_out[bv * 64 + tid] = z * nxts[tid] + (1.f - z) * encs[tid];
  }
}

// ---- decoder hidden (linear) + dual variable dv, 8 nodes/block ----
#define DNV 8
__global__ void dec_dual_kernel(const float* __restrict__ enc, const float* __restrict__ dw1,
                                const float* __restrict__ db1, const float* __restrict__ uw1,
                                const float* __restrict__ ub1, const float* __restrict__ uw2,
                                const float* __restrict__ ub2, float* __restrict__ hid,
                                float* __restrict__ dv) {
  int bv0 = blockIdx.x * DNV;
  int j = threadIdx.x;  // 64
  __shared__ float es[DNV][64];
#pragma unroll
  for (int n = 0; n < DNV; ++n) es[n][j] = enc[(bv0 + n) * 64 + j];
  __syncthreads();
  float hj[DNV], uj[DNV];
#pragma unroll
  for (int n = 0; n < DNV; ++n) { hj[n] = db1[j]; uj[n] = ub1[j]; }
  for (int f = 0; f < 64; ++f) {
    float a = dw1[f * 64 + j], c = uw1[f * 64 + j];
#pragma unroll
    for (int n = 0; n < DNV; ++n) {
      hj[n] += es[n][f] * a;
      uj[n] += es[n][f] * c;
    }
  }
  float w2v = uw2[j];
#pragma unroll
  for (int n = 0; n < DNV; ++n) {
    hid[(bv0 + n) * 64 + j] = hj[n];  // NO relu: decoder is linear
    float s = wave_sum(uj[n] * w2v);
    if (j == 0) dv[bv0 + n] = s + ub2[0];
  }
}

__global__ void transpose_w2(const float* __restrict__ w2, float* __restrict__ w2t) {
  int w = blockIdx.x, j = threadIdx.x;
  w2t[w * 64 + j] = w2[j * V + w];
}

// ---- flow weights: softmax over out-edges of pred^2, scattered DIRECTLY into
//      CSC-ordered per-batch edge array fwe; also row sum of fw^2 ----
__global__ void fw_kernel(const float* __restrict__ hid, const float* __restrict__ w2t,
                          const float* __restrict__ b2, const int* __restrict__ nbr,
                          const int* __restrict__ deg, const int* __restrict__ csc_pos,
                          float* __restrict__ fwe, float* __restrict__ rssq) {
  int bv = blockIdx.x;
  int b = bv >> 10, v = bv & 1023;
  int lane = threadIdx.x;  // 64
  float hj = hid[bv * 64 + lane];
  int dvv = deg[v];
  float myp = -1e30f;
  for (int k = 0; k < dvv; ++k) {
    int w = nbr[v * CAP + k];  // wave-uniform
    float d = wave_sum(hj * w2t[w * 64 + lane]);
    float pp = d + b2[w];
    pp = pp * pp;
    if (lane == k) myp = pp;
  }
  float m = wave_max(myp);
  float e = (lane < dvv) ? __expf(myp - m) : 0.f;
  float s = wave_sum(e);
  float coef = e / s;
  if (lane < dvv) fwe[(size_t)b * MAXNNZ + csc_pos[v * CAP + lane]] = coef;
  float r = wave_sum(coef * coef);
  if (lane == 0) rssq[bv] = r;
}

// ---- flow iterations entirely in LDS (coalesced staging) + dual cost ----
__global__ __launch_bounds__(1024) void flow_dual_kernel(
    const float* __restrict__ fwe, const float* __restrict__ rssq,
    const unsigned short* __restrict__ c_src, const int* __restrict__ in_off,
    const float* __restrict__ dv, const float* __restrict__ demands,
    const int* __restrict__ nbr_out, const int* __restrict__ deg_out,
    float* __restrict__ partial) {
  int b = blockIdx.x;
  int v = threadIdx.x;  // 1024
  __shared__ float lfw[MAXNNZ];            // 80 KB
  __shared__ unsigned short lsrc[MAXNNZ];  // 40 KB
  __shared__ float oA[V], oB[V];           // 8 KB
  __shared__ float dvs[V];                 // 4 KB
  __shared__ float red[16];
  int nnz = in_off[V];
  if (nnz > MAXNNZ) nnz = MAXNNZ;
  const float* fwb = fwe + (size_t)b * MAXNNZ;
  for (int e = v; e < nnz; e += V) {  // fully coalesced staging
    lfw[e] = fwb[e];
    lsrc[e] = c_src[e];
  }
  float dem = demands[b * V + v];
  dvs[v] = dv[b * V + v];
  int o0 = in_off[v], o1 = in_off[v + 1];
  if (o1 > nnz) o1 = nnz;
  if (o0 > nnz) o0 = nnz;
  oA[v] = fmaxf(-dem, 0.f);  // o_1 = relu(-demand)
  __syncthreads();
  float* cur = oA;
  float* nxt = oB;
  for (int it = 0; it < 9; ++it) {
    float inflow = 0.f;
    for (int e = o0; e < o1; ++e) inflow += lfw[e] * cur[lsrc[e]];
    nxt[v] = fmaxf(inflow - dem, 0.f);
    __syncthreads();
    float* tmp = cur; cur = nxt; nxt = tmp;
  }
  float o10 = cur[v];
  float local = o10 * o10 * rssq[b * V + v];  // flow_cost contribution
  // dual: loss_b = flow_cost + 0.25*sum_edges relu(dv_v - dv_w)^2 + sum_v dv_v*dem_v
  float dvv = dvs[v];
  int dout = deg_out[v];
  float acc = 0.f;
  for (int k = 0; k < dout; ++k) {
    float diff = dvv - dvs[nbr_out[v * CAP + k]];
    if (diff > 0.f) acc += diff * diff;
  }
  local += 0.25f * acc + dvv * dem;
  local = wave_sum(local);
  if ((v & 63) == 0) red[v >> 6] = local;
  __syncthreads();
  if (v < 16) {
    float r = red[v];
    for (int o = 8; o > 0; o >>= 1) r += __shfl_xor(r, o, 16);
    if (v == 0) partial[b] = r;
  }
}

__global__ void final_kernel(const float* __restrict__ partial, float* __restrict__ out) {
  if (threadIdx.x == 0) {
    float s = 0.f;
    for (int b = 0; b < B; ++b) s += partial[b];
    out[0] = s * (1.0f / B);
  }
}

extern "C" void kernel_launch(void* const* d_in, const int* in_sizes, int n_in,
                              void* d_out, int out_size, void* d_ws, size_t ws_size,
                              hipStream_t stream) {
  const float* demands = (const float*)d_in[0];
  const float* emb     = (const float*)d_in[1];
  const float* adj     = (const float*)d_in[2];
  const float* enc_w1  = (const float*)d_in[3];
  const float* enc_b1  = (const float*)d_in[4];
  const float* enc_w2  = (const float*)d_in[5];
  const float* enc_b2  = (const float*)d_in[6];
  const float* gat_w   = (const float*)d_in[7];
  const float* gat_a1  = (const float*)d_in[8];
  const float* gat_a2  = (const float*)d_in[9];
  const float* gate_w  = (const float*)d_in[10];
  const float* gate_u  = (const float*)d_in[11];
  const float* gate_b  = (const float*)d_in[12];
  const float* dec_w1  = (const float*)d_in[13];
  const float* dec_b1  = (const float*)d_in[14];
  const float* dec_w2  = (const float*)d_in[15];
  const float* dec_b2  = (const float*)d_in[16];
  const float* dual_w1 = (const float*)d_in[17];
  const float* dual_b1 = (const float*)d_in[18];
  const float* dual_w2 = (const float*)d_in[19];
  const float* dual_b2 = (const float*)d_in[20];

  char* p = (char*)d_ws;
  auto alloc = [&](size_t n) { void* r = (void*)p; p += (n + 255) & ~(size_t)255; return r; };
  int* nbr_out   = (int*)alloc((size_t)V * CAP * 4);
  int* deg_out   = (int*)alloc((size_t)V * 4);
  int* deg_in    = (int*)alloc((size_t)V * 4);
  int* in_off    = (int*)alloc((size_t)(V + 1) * 4);
  unsigned short* c_src = (unsigned short*)alloc((size_t)MAXNNZ * 2);
  int* csc_pos   = (int*)alloc((size_t)V * CAP * 4);
  float* fwe     = (float*)alloc((size_t)B * MAXNNZ * 4);
  float* w2t     = (float*)alloc((size_t)HIDN * V * 4);
  float* encA    = (float*)alloc((size_t)B * V * 64 * 4);
  float* encB    = (float*)alloc((size_t)B * V * 64 * 4);
  float* t       = (float*)alloc((size_t)B * H * V * 64 * 4);
  float* s_self  = (float*)alloc((size_t)B * H * V * 4);
  float* s_nbr   = (float*)alloc((size_t)B * H * V * 4);
  float* hid     = (float*)alloc((size_t)B * V * 64 * 4);
  float* dv      = (float*)alloc((size_t)B * V * 4);
  float* rssq    = (float*)alloc((size_t)B * V * 4);
  float* partial = (float*)alloc((size_t)B * 4);

  build_csr<<<V, 64, 0, stream>>>(adj, nbr_out, deg_out);
  colcount_kernel<<<V / 64, 1024, 0, stream>>>(adj, deg_in);
  scan_kernel<<<1, V, 0, stream>>>(deg_in, in_off);
  build_csc2<<<V / 64, 1024, 0, stream>>>(adj, nbr_out, deg_out, in_off, c_src, csc_pos);
  enc_kernel<<<B * V / ENV, 64, 0, stream>>>(demands, emb, enc_w1, enc_b1, enc_w2, enc_b2, encA);
  float* cur = encA;
  float* nxt = encB;
  for (int l = 0; l < 2; ++l) {
    t_kernel<<<B * V / TNV, 256, 0, stream>>>(cur, gat_w, gat_a1, gat_a2, t, s_self, s_nbr);
    gat_kernel<<<B * V, 256, 0, stream>>>(cur, t, s_self, s_nbr, nbr_out, deg_out,
                                          gate_w, gate_u, gate_b, nxt);
    float* tmp = cur; cur = nxt; nxt = tmp;
  }
  transpose_w2<<<V, 64, 0, stream>>>(dec_w2, w2t);
  dec_dual_kernel<<<B * V / DNV, 64, 0, stream>>>(cur, dec_w1, dec_b1, dual_w1, dual_b1,
                                                  dual_w2, dual_b2, hid, dv);
  fw_kernel<<<B * V, 64, 0, stream>>>(hid, w2t, dec_b2, nbr_out, deg_out, csc_pos, fwe, rssq);
  flow_dual_kernel<<<B, 1024, 0, stream>>>(fwe, rssq, c_src, in_off, dv, demands,
                                           nbr_out, deg_out, partial);
  final_kernel<<<1, 64, 0, stream>>>(partial, (float*)d_out);
}

// Round 4
// 238.926 us; speedup vs baseline: 1.7146x; 1.7146x over previous
//
#include <hip/hip_runtime.h>
#include <math.h>

#define B 8
#define V 1024
#define E 32
#define F 64
#define H 4
#define HIDN 64
#define CAP 64        // max out-degree capacity; E[deg]=17, P(deg>64) ~ 1e-21
#define MAXNNZ 20480  // nnz ~ 17390 +/- 128; +24 sigma headroom

__device__ __forceinline__ float wave_sum(float v) {
  for (int o = 32; o > 0; o >>= 1) v += __shfl_xor(v, o);
  return v;
}
__device__ __forceinline__ float wave_max(float v) {
  for (int o = 32; o > 0; o >>= 1) v = fmaxf(v, __shfl_xor(v, o));
  return v;
}

// ---- adjacency -> CSR out-neighbor lists (row-coalesced ballot compaction) ----
__global__ void build_csr(const float* __restrict__ adj, int* __restrict__ nbr,
                          int* __restrict__ deg) {
  int v = blockIdx.x;
  int lane = threadIdx.x;
  int base = 0;
  for (int c = 0; c < V; c += 64) {
    float a = adj[v * V + c + lane];
    unsigned long long m = __ballot(a > 0.5f);
    int pos = __popcll(m & ((1ull << lane) - 1ull));
    if (a > 0.5f && base + pos < CAP) nbr[v * CAP + base + pos] = c + lane;
    base += __popcll(m);
  }
  if (lane == 0) deg[v] = (base < CAP) ? base : CAP;
}

// ---- in-degree per column, row-coalesced ----
__global__ __launch_bounds__(1024) void colcount_kernel(const float* __restrict__ adj,
                                                        int* __restrict__ deg_in) {
  __shared__ int part[16][64];
  int w0 = blockIdx.x * 64;
  int t = threadIdx.x;
  int wave = t >> 6, lane = t & 63;
  int col = w0 + lane;
  int cnt = 0;
  for (int r = wave; r < V; r += 16) cnt += (adj[(size_t)r * V + col] > 0.5f) ? 1 : 0;
  part[wave][lane] = cnt;
  __syncthreads();
  if (t < 64) {
    int s = 0;
#pragma unroll
    for (int i = 0; i < 16; ++i) s += part[i][t];
    deg_in[w0 + t] = s;
  }
}

// ---- exclusive prefix scan of deg_in -> in_off[V+1], single block ----
__global__ void scan_kernel(const int* __restrict__ deg_in, int* __restrict__ in_off) {
  __shared__ int s[V];
  int v = threadIdx.x;
  int d = deg_in[v];
  s[v] = d;
  __syncthreads();
  for (int o = 1; o < V; o <<= 1) {
    int t = (v >= o) ? s[v - o] : 0;
    __syncthreads();
    s[v] += t;
    __syncthreads();
  }
  in_off[v] = s[v] - d;  // exclusive
  if (v == V - 1) in_off[V] = s[v];
}

// ---- CSC edge list via LDS tile transpose (adj read row-coalesced) ----
// c_src[idx] = source node, c_w[idx] = dest node of idx-th CSC edge.
// NO searching here — the slow inverse map is built by kkmap_kernel.
__global__ __launch_bounds__(1024) void build_csc2(const float* __restrict__ adj,
                                                   const int* __restrict__ in_off,
                                                   unsigned short* __restrict__ c_src,
                                                   unsigned short* __restrict__ c_w) {
  __shared__ float tile[64][65];
  __shared__ int cbase[64];
  int w0 = blockIdx.x * 64;
  int t = threadIdx.x;
  int wave = t >> 6, lane = t & 63;
  if (t < 64) cbase[t] = in_off[w0 + t];
  __syncthreads();
  for (int c = 0; c < 16; ++c) {
#pragma unroll
    for (int i = 0; i < 4; ++i) {
      int e = t + i * 1024;
      int r = e >> 6, col = e & 63;
      tile[r][col] = adj[(size_t)(c * 64 + r) * V + w0 + col];
    }
    __syncthreads();
#pragma unroll
    for (int cc = 0; cc < 4; ++cc) {
      int col = wave * 4 + cc;
      float a = tile[lane][col];
      unsigned long long m = __ballot(a > 0.5f);
      int pos = __popcll(m & ((1ull << lane) - 1ull));
      if (a > 0.5f) {
        int idx = cbase[col] + pos;
        c_src[idx] = (unsigned short)(c * 64 + lane);
        c_w[idx] = (unsigned short)(w0 + col);
      }
      if (lane == 0) cbase[col] += __popcll(m);
    }
    __syncthreads();
  }
}

// ---- inverse map: csc_pos[v*CAP + k] = CSC index of v's k-th out-edge ----
// One thread per edge; independent short match loops, latency hidden by TLP.
__global__ void kkmap_kernel(const unsigned short* __restrict__ c_src,
                             const unsigned short* __restrict__ c_w,
                             const int* __restrict__ nbr_out,
                             const int* __restrict__ in_off,
                             int* __restrict__ csc_pos) {
  int idx = blockIdx.x * 256 + threadIdx.x;
  int nnz = in_off[V];
  if (nnz > MAXNNZ) nnz = MAXNNZ;
  if (idx >= nnz) return;
  int v = c_src[idx];
  int w = c_w[idx];
  const int* row = nbr_out + v * CAP;
  for (int k = 0; k < CAP; ++k) {
    if (row[k] == w) { csc_pos[v * CAP + k] = idx; break; }
  }
}

// ---- encoder MLP, 8 nodes/block to amortize weight reads ----
#define ENV 8
__global__ void enc_kernel(const float* __restrict__ demands, const float* __restrict__ emb,
                           const float* __restrict__ w1, const float* __restrict__ b1,
                           const float* __restrict__ w2, const float* __restrict__ b2,
                           float* __restrict__ enc) {
  int bv0 = blockIdx.x * ENV;
  int b = bv0 >> 10, v0 = bv0 & 1023;
  int j = threadIdx.x;  // 64
  __shared__ float xs[ENV][E + 1];
  __shared__ float hs[ENV][64];
#pragma unroll
  for (int n = 0; n < ENV; ++n) {
    if (j < E) xs[n][j] = emb[(v0 + n) * E + j];
    else if (j == E) xs[n][E] = demands[b * V + v0 + n];
  }
  __syncthreads();
  float h[ENV];
#pragma unroll
  for (int n = 0; n < ENV; ++n) h[n] = b1[j];
  for (int i = 0; i < E + 1; ++i) {
    float wv = w1[i * 64 + j];
#pragma unroll
    for (int n = 0; n < ENV; ++n) h[n] += xs[n][i] * wv;
  }
#pragma unroll
  for (int n = 0; n < ENV; ++n) hs[n][j] = fmaxf(h[n], 0.f);
  __syncthreads();
  float o[ENV];
#pragma unroll
  for (int n = 0; n < ENV; ++n) o[n] = b2[j];
  for (int i = 0; i < 64; ++i) {
    float wv = w2[i * 64 + j];
#pragma unroll
    for (int n = 0; n < ENV; ++n) o[n] += hs[n][i] * wv;
  }
#pragma unroll
  for (int n = 0; n < ENV; ++n) enc[(bv0 + n) * 64 + j] = fmaxf(o[n], 0.f);
}

// ---- t = einsum('bvf,hfg->bhvg') + attention score projections, 8 nodes/block ----
#define TNV 8
__global__ void t_kernel(const float* __restrict__ enc, const float* __restrict__ gat_w,
                         const float* __restrict__ a1, const float* __restrict__ a2,
                         float* __restrict__ t, float* __restrict__ s_self,
                         float* __restrict__ s_nbr) {
  int bv0 = blockIdx.x * TNV;
  int b = bv0 >> 10, v0 = bv0 & 1023;
  int tid = threadIdx.x;  // 256
  int h = tid >> 6, g = tid & 63;
  __shared__ float es[TNV][64];
  for (int i = tid; i < TNV * 64; i += 256) es[i >> 6][i & 63] = enc[bv0 * 64 + i];
  __syncthreads();
  float acc[TNV];
#pragma unroll
  for (int n = 0; n < TNV; ++n) acc[n] = 0.f;
  const float* w = gat_w + h * 64 * 64 + g;
  for (int f = 0; f < 64; ++f) {
    float wf = w[f * 64];
#pragma unroll
    for (int n = 0; n < TNV; ++n) acc[n] += es[n][f] * wf;
  }
  float a1v = a1[h * 64 + g], a2v = a2[h * 64 + g];
#pragma unroll
  for (int n = 0; n < TNV; ++n) {
    t[((size_t)(b * H + h) * V + (v0 + n)) * 64 + g] = acc[n];
    float v1 = wave_sum(acc[n] * a1v);
    float v2 = wave_sum(acc[n] * a2v);
    if (g == 0) {
      s_self[(b * H + h) * V + (v0 + n)] = v1;
      s_nbr[(b * H + h) * V + (v0 + n)] = v2;
    }
  }
}

// ---- sparse GAT attention + head-mean + GRU-style gate ----
__global__ void gat_kernel(const float* __restrict__ enc_in, const float* __restrict__ t,
                           const float* __restrict__ s_self, const float* __restrict__ s_nbr,
                           const int* __restrict__ nbr, const int* __restrict__ deg,
                           const float* __restrict__ gate_w, const float* __restrict__ gate_u,
                           const float* __restrict__ gate_b, float* __restrict__ enc_out) {
  int bv = blockIdx.x;
  int b = bv >> 10, v = bv & 1023;
  int tid = threadIdx.x;
  int h = tid >> 6, lane = tid & 63;
  int dvv = deg[v];
  int wk = (lane < dvv) ? nbr[v * CAP + lane] : 0;
  float logit = -1e30f;
  if (lane < dvv) {
    float x = s_self[(b * H + h) * V + v] + s_nbr[(b * H + h) * V + wk];
    logit = (x > 0.f) ? x : 0.2f * x;  // leaky_relu 0.2
  }
  float m = wave_max(logit);
  float e = (lane < dvv) ? __expf(logit - m) : 0.f;
  float s = wave_sum(e);
  float coef = e / s;
  const float* tb = t + (size_t)(b * H + h) * (V * 64);
  float acc = 0.f;
  for (int k = 0; k < dvv; ++k) {
    float c = __shfl(coef, k);
    int w = __shfl(wk, k);
    acc += c * tb[w * 64 + lane];
  }
  __shared__ float hsum[4][64];
  __shared__ float nxts[64], encs[64];
  hsum[h][lane] = acc;
  __syncthreads();
  if (tid < 64) {
    float s4 = hsum[0][tid] + hsum[1][tid] + hsum[2][tid] + hsum[3][tid];
    nxts[tid] = fmaxf(0.25f * s4, 0.f);
    encs[tid] = enc_in[bv * 64 + tid];
  }
  __syncthreads();
  float part = 0.f;
  for (int f = h * 16; f < h * 16 + 16; ++f)
    part += nxts[f] * gate_w[f * 64 + lane] + encs[f] * gate_u[f * 64 + lane];
  __syncthreads();
  hsum[h][lane] = part;
  __syncthreads();
  if (tid < 64) {
    float zs = hsum[0][tid] + hsum[1][tid] + hsum[2][tid] + hsum[3][tid] + gate_b[tid];
    float z = 1.f / (1.f + __expf(-zs));
    enc_out[bv * 64 + tid] = z * nxts[tid] + (1.f - z) * encs[tid];
  }
}

// ---- decoder hidden (linear) + dual variable dv, 8 nodes/block ----
#define DNV 8
__global__ void dec_dual_kernel(const float* __restrict__ enc, const float* __restrict__ dw1,
                                const float* __restrict__ db1, const float* __restrict__ uw1,
                                const float* __restrict__ ub1, const float* __restrict__ uw2,
                                const float* __restrict__ ub2, float* __restrict__ hid,
                                float* __restrict__ dv) {
  int bv0 = blockIdx.x * DNV;
  int j = threadIdx.x;  // 64
  __shared__ float es[DNV][64];
#pragma unroll
  for (int n = 0; n < DNV; ++n) es[n][j] = enc[(bv0 + n) * 64 + j];
  __syncthreads();
  float hj[DNV], uj[DNV];
#pragma unroll
  for (int n = 0; n < DNV; ++n) { hj[n] = db1[j]; uj[n] = ub1[j]; }
  for (int f = 0; f < 64; ++f) {
    float a = dw1[f * 64 + j], c = uw1[f * 64 + j];
#pragma unroll
    for (int n = 0; n < DNV; ++n) {
      hj[n] += es[n][f] * a;
      uj[n] += es[n][f] * c;
    }
  }
  float w2v = uw2[j];
#pragma unroll
  for (int n = 0; n < DNV; ++n) {
    hid[(bv0 + n) * 64 + j] = hj[n];  // NO relu: decoder is linear
    float s = wave_sum(uj[n] * w2v);
    if (j == 0) dv[bv0 + n] = s + ub2[0];
  }
}

__global__ void transpose_w2(const float* __restrict__ w2, float* __restrict__ w2t) {
  int w = blockIdx.x, j = threadIdx.x;
  w2t[w * 64 + j] = w2[j * V + w];
}

// ---- flow weights: softmax over out-edges of pred^2, scattered DIRECTLY into
//      CSC-ordered per-batch edge array fwe; also row sum of fw^2 ----
__global__ void fw_kernel(const float* __restrict__ hid, const float* __restrict__ w2t,
                          const float* __restrict__ b2, const int* __restrict__ nbr,
                          const int* __restrict__ deg, const int* __restrict__ csc_pos,
                          float* __restrict__ fwe, float* __restrict__ rssq) {
  int bv = blockIdx.x;
  int b = bv >> 10, v = bv & 1023;
  int lane = threadIdx.x;  // 64
  float hj = hid[bv * 64 + lane];
  int dvv = deg[v];
  float myp = -1e30f;
  for (int k = 0; k < dvv; ++k) {
    int w = nbr[v * CAP + k];  // wave-uniform
    float d = wave_sum(hj * w2t[w * 64 + lane]);
    float pp = d + b2[w];
    pp = pp * pp;
    if (lane == k) myp = pp;
  }
  float m = wave_max(myp);
  float e = (lane < dvv) ? __expf(myp - m) : 0.f;
  float s = wave_sum(e);
  float coef = e / s;
  if (lane < dvv) fwe[(size_t)b * MAXNNZ + csc_pos[v * CAP + lane]] = coef;
  float r = wave_sum(coef * coef);
  if (lane == 0) rssq[bv] = r;
}

// ---- flow iterations entirely in LDS (coalesced staging) + dual cost ----
__global__ __launch_bounds__(1024) void flow_dual_kernel(
    const float* __restrict__ fwe, const float* __restrict__ rssq,
    const unsigned short* __restrict__ c_src, const int* __restrict__ in_off,
    const float* __restrict__ dv, const float* __restrict__ demands,
    const int* __restrict__ nbr_out, const int* __restrict__ deg_out,
    float* __restrict__ partial) {
  int b = blockIdx.x;
  int v = threadIdx.x;  // 1024
  __shared__ float lfw[MAXNNZ];            // 80 KB
  __shared__ unsigned short lsrc[MAXNNZ];  // 40 KB
  __shared__ float oA[V], oB[V];           // 8 KB
  __shared__ float dvs[V];                 // 4 KB
  __shared__ float red[16];
  int nnz = in_off[V];
  if (nnz > MAXNNZ) nnz = MAXNNZ;
  const float* fwb = fwe + (size_t)b * MAXNNZ;
  for (int e = v; e < nnz; e += V) {  // fully coalesced staging
    lfw[e] = fwb[e];
    lsrc[e] = c_src[e];
  }
  float dem = demands[b * V + v];
  dvs[v] = dv[b * V + v];
  int o0 = in_off[v], o1 = in_off[v + 1];
  if (o1 > nnz) o1 = nnz;
  if (o0 > nnz) o0 = nnz;
  oA[v] = fmaxf(-dem, 0.f);  // o_1 = relu(-demand)
  __syncthreads();
  float* cur = oA;
  float* nxt = oB;
  for (int it = 0; it < 9; ++it) {
    float inflow = 0.f;
    for (int e = o0; e < o1; ++e) inflow += lfw[e] * cur[lsrc[e]];
    nxt[v] = fmaxf(inflow - dem, 0.f);
    __syncthreads();
    float* tmp = cur; cur = nxt; nxt = tmp;
  }
  float o10 = cur[v];
  float local = o10 * o10 * rssq[b * V + v];  // flow_cost contribution
  // dual: loss_b = flow_cost + 0.25*sum_edges relu(dv_v - dv_w)^2 + sum_v dv_v*dem_v
  float dvv = dvs[v];
  int dout = deg_out[v];
  float acc = 0.f;
  for (int k = 0; k < dout; ++k) {
    float diff = dvv - dvs[nbr_out[v * CAP + k]];
    if (diff > 0.f) acc += diff * diff;
  }
  local += 0.25f * acc + dvv * dem;
  local = wave_sum(local);
  if ((v & 63) == 0) red[v >> 6] = local;
  __syncthreads();
  if (v < 16) {
    float r = red[v];
    for (int o = 8; o > 0; o >>= 1) r += __shfl_xor(r, o, 16);
    if (v == 0) partial[b] = r;
  }
}

__global__ void final_kernel(const float* __restrict__ partial, float* __restrict__ out) {
  if (threadIdx.x == 0) {
    float s = 0.f;
    for (int b = 0; b < B; ++b) s += partial[b];
    out[0] = s * (1.0f / B);
  }
}

extern "C" void kernel_launch(void* const* d_in, const int* in_sizes, int n_in,
                              void* d_out, int out_size, void* d_ws, size_t ws_size,
                              hipStream_t stream) {
  const float* demands = (const float*)d_in[0];
  const float* emb     = (const float*)d_in[1];
  const float* adj     = (const float*)d_in[2];
  const float* enc_w1  = (const float*)d_in[3];
  const float* enc_b1  = (const float*)d_in[4];
  const float* enc_w2  = (const float*)d_in[5];
  const float* enc_b2  = (const float*)d_in[6];
  const float* gat_w   = (const float*)d_in[7];
  const float* gat_a1  = (const float*)d_in[8];
  const float* gat_a2  = (const float*)d_in[9];
  const float* gate_w  = (const float*)d_in[10];
  const float* gate_u  = (const float*)d_in[11];
  const float* gate_b  = (const float*)d_in[12];
  const float* dec_w1  = (const float*)d_in[13];
  const float* dec_b1  = (const float*)d_in[14];
  const float* dec_w2  = (const float*)d_in[15];
  const float* dec_b2  = (const float*)d_in[16];
  const float* dual_w1 = (const float*)d_in[17];
  const float* dual_b1 = (const float*)d_in[18];
  const float* dual_w2 = (const float*)d_in[19];
  const float* dual_b2 = (const float*)d_in[20];

  char* p = (char*)d_ws;
  auto alloc = [&](size_t n) { void* r = (void*)p; p += (n + 255) & ~(size_t)255; return r; };
  int* nbr_out   = (int*)alloc((size_t)V * CAP * 4);
  int* deg_out   = (int*)alloc((size_t)V * 4);
  int* deg_in    = (int*)alloc((size_t)V * 4);
  int* in_off    = (int*)alloc((size_t)(V + 1) * 4);
  unsigned short* c_src = (unsigned short*)alloc((size_t)MAXNNZ * 2);
  unsigned short* c_w   = (unsigned short*)alloc((size_t)MAXNNZ * 2);
  int* csc_pos   = (int*)alloc((size_t)V * CAP * 4);
  float* fwe     = (float*)alloc((size_t)B * MAXNNZ * 4);
  float* w2t     = (float*)alloc((size_t)HIDN * V * 4);
  float* encA    = (float*)alloc((size_t)B * V * 64 * 4);
  float* encB    = (float*)alloc((size_t)B * V * 64 * 4);
  float* t       = (float*)alloc((size_t)B * H * V * 64 * 4);
  float* s_self  = (float*)alloc((size_t)B * H * V * 4);
  float* s_nbr   = (float*)alloc((size_t)B * H * V * 4);
  float* hid     = (float*)alloc((size_t)B * V * 64 * 4);
  float* dv      = (float*)alloc((size_t)B * V * 4);
  float* rssq    = (float*)alloc((size_t)B * V * 4);
  float* partial = (float*)alloc((size_t)B * 4);

  build_csr<<<V, 64, 0, stream>>>(adj, nbr_out, deg_out);
  colcount_kernel<<<V / 64, 1024, 0, stream>>>(adj, deg_in);
  scan_kernel<<<1, V, 0, stream>>>(deg_in, in_off);
  build_csc2<<<V / 64, 1024, 0, stream>>>(adj, in_off, c_src, c_w);
  kkmap_kernel<<<(MAXNNZ + 255) / 256, 256, 0, stream>>>(c_src, c_w, nbr_out, in_off, csc_pos);
  enc_kernel<<<B * V / ENV, 64, 0, stream>>>(demands, emb, enc_w1, enc_b1, enc_w2, enc_b2, encA);
  float* cur = encA;
  float* nxt = encB;
  for (int l = 0; l < 2; ++l) {
    t_kernel<<<B * V / TNV, 256, 0, stream>>>(cur, gat_w, gat_a1, gat_a2, t, s_self, s_nbr);
    gat_kernel<<<B * V, 256, 0, stream>>>(cur, t, s_self, s_nbr, nbr_out, deg_out,
                                          gate_w, gate_u, gate_b, nxt);
    float* tmp = cur; cur = nxt; nxt = tmp;
  }
  transpose_w2<<<V, 64, 0, stream>>>(dec_w2, w2t);
  dec_dual_kernel<<<B * V / DNV, 64, 0, stream>>>(cur, dec_w1, dec_b1, dual_w1, dual_b1,
                                                  dual_w2, dual_b2, hid, dv);
  fw_kernel<<<B * V, 64, 0, stream>>>(hid, w2t, dec_b2, nbr_out, deg_out, csc_pos, fwe, rssq);
  flow_dual_kernel<<<B, 1024, 0, stream>>>(fwe, rssq, c_src, in_off, dv, demands,
                                           nbr_out, deg_out, partial);
  final_kernel<<<1, 64, 0, stream>>>(partial, (float*)d_out);
}

// Round 5
// 198.898 us; speedup vs baseline: 2.0597x; 1.2012x over previous
//
#include <hip/hip_runtime.h>
#include <math.h>

#define B 8
#define V 1024
#define E 32
#define F 64
#define H 4
#define HIDN 64
#define CAP 64        // max out-degree capacity; E[deg]=17, P(deg>64) ~ 1e-21
#define MAXNNZ 20480  // nnz ~ 17390 +/- 128; +24 sigma headroom

// XCD-aware decode: blockIdx round-robins across 8 XCDs on MI355X, and B==8.
// b = blockIdx & 7 pins each batch to one XCD -> per-XCD working set (t[b] ~1MB)
// fits the 4MB per-XCD L2 instead of all XCDs re-fetching all of t from HBM.

__device__ __forceinline__ float wave_sum(float v) {
  for (int o = 32; o > 0; o >>= 1) v += __shfl_xor(v, o);
  return v;
}
__device__ __forceinline__ float wave_max(float v) {
  for (int o = 32; o > 0; o >>= 1) v = fmaxf(v, __shfl_xor(v, o));
  return v;
}

// ---- adjacency -> CSR out-neighbor lists (row-coalesced ballot compaction) ----
__global__ void build_csr(const float* __restrict__ adj, int* __restrict__ nbr,
                          int* __restrict__ deg) {
  int v = blockIdx.x;
  int lane = threadIdx.x;
  int base = 0;
  for (int c = 0; c < V; c += 64) {
    float a = adj[v * V + c + lane];
    unsigned long long m = __ballot(a > 0.5f);
    int pos = __popcll(m & ((1ull << lane) - 1ull));
    if (a > 0.5f && base + pos < CAP) nbr[v * CAP + base + pos] = c + lane;
    base += __popcll(m);
  }
  if (lane == 0) deg[v] = (base < CAP) ? base : CAP;
}

// ---- in-degree per column, row-coalesced ----
__global__ __launch_bounds__(1024) void colcount_kernel(const float* __restrict__ adj,
                                                        int* __restrict__ deg_in) {
  __shared__ int part[16][64];
  int w0 = blockIdx.x * 64;
  int t = threadIdx.x;
  int wave = t >> 6, lane = t & 63;
  int col = w0 + lane;
  int cnt = 0;
  for (int r = wave; r < V; r += 16) cnt += (adj[(size_t)r * V + col] > 0.5f) ? 1 : 0;
  part[wave][lane] = cnt;
  __syncthreads();
  if (t < 64) {
    int s = 0;
#pragma unroll
    for (int i = 0; i < 16; ++i) s += part[i][t];
    deg_in[w0 + t] = s;
  }
}

// ---- exclusive prefix scan of deg_in -> in_off[V+1], single block ----
__global__ void scan_kernel(const int* __restrict__ deg_in, int* __restrict__ in_off) {
  __shared__ int s[V];
  int v = threadIdx.x;
  int d = deg_in[v];
  s[v] = d;
  __syncthreads();
  for (int o = 1; o < V; o <<= 1) {
    int t = (v >= o) ? s[v - o] : 0;
    __syncthreads();
    s[v] += t;
    __syncthreads();
  }
  in_off[v] = s[v] - d;  // exclusive
  if (v == V - 1) in_off[V] = s[v];
}

// ---- CSC edge list via LDS tile transpose (adj read row-coalesced) ----
__global__ __launch_bounds__(1024) void build_csc2(const float* __restrict__ adj,
                                                   const int* __restrict__ in_off,
                                                   unsigned short* __restrict__ c_src,
                                                   unsigned short* __restrict__ c_w) {
  __shared__ float tile[64][65];
  __shared__ int cbase[64];
  int w0 = blockIdx.x * 64;
  int t = threadIdx.x;
  int wave = t >> 6, lane = t & 63;
  if (t < 64) cbase[t] = in_off[w0 + t];
  __syncthreads();
  for (int c = 0; c < 16; ++c) {
#pragma unroll
    for (int i = 0; i < 4; ++i) {
      int e = t + i * 1024;
      int r = e >> 6, col = e & 63;
      tile[r][col] = adj[(size_t)(c * 64 + r) * V + w0 + col];
    }
    __syncthreads();
#pragma unroll
    for (int cc = 0; cc < 4; ++cc) {
      int col = wave * 4 + cc;
      float a = tile[lane][col];
      unsigned long long m = __ballot(a > 0.5f);
      int pos = __popcll(m & ((1ull << lane) - 1ull));
      if (a > 0.5f) {
        int idx = cbase[col] + pos;
        c_src[idx] = (unsigned short)(c * 64 + lane);
        c_w[idx] = (unsigned short)(w0 + col);
      }
      if (lane == 0) cbase[col] += __popcll(m);
    }
    __syncthreads();
  }
}

// ---- inverse map: csc_pos[v*CAP + k] = CSC index of v's k-th out-edge ----
__global__ void kkmap_kernel(const unsigned short* __restrict__ c_src,
                             const unsigned short* __restrict__ c_w,
                             const int* __restrict__ nbr_out,
                             const int* __restrict__ in_off,
                             int* __restrict__ csc_pos) {
  int idx = blockIdx.x * 256 + threadIdx.x;
  int nnz = in_off[V];
  if (nnz > MAXNNZ) nnz = MAXNNZ;
  if (idx >= nnz) return;
  int v = c_src[idx];
  int w = c_w[idx];
  const int* row = nbr_out + v * CAP;
  for (int k = 0; k < CAP; ++k) {
    if (row[k] == w) { csc_pos[v * CAP + k] = idx; break; }
  }
}

// ---- encoder MLP, 8 nodes/block, XCD-pinned by batch ----
#define ENV 8
__global__ void enc_kernel(const float* __restrict__ demands, const float* __restrict__ emb,
                           const float* __restrict__ w1, const float* __restrict__ b1,
                           const float* __restrict__ w2, const float* __restrict__ b2,
                           float* __restrict__ enc) {
  int b = blockIdx.x & 7;
  int v0 = (blockIdx.x >> 3) * ENV;
  int bv0 = b * V + v0;
  int j = threadIdx.x;  // 64
  __shared__ float xs[ENV][E + 1];
  __shared__ float hs[ENV][64];
#pragma unroll
  for (int n = 0; n < ENV; ++n) {
    if (j < E) xs[n][j] = emb[(v0 + n) * E + j];
    else if (j == E) xs[n][E] = demands[b * V + v0 + n];
  }
  __syncthreads();
  float h[ENV];
#pragma unroll
  for (int n = 0; n < ENV; ++n) h[n] = b1[j];
  for (int i = 0; i < E + 1; ++i) {
    float wv = w1[i * 64 + j];
#pragma unroll
    for (int n = 0; n < ENV; ++n) h[n] += xs[n][i] * wv;
  }
#pragma unroll
  for (int n = 0; n < ENV; ++n) hs[n][j] = fmaxf(h[n], 0.f);
  __syncthreads();
  float o[ENV];
#pragma unroll
  for (int n = 0; n < ENV; ++n) o[n] = b2[j];
  for (int i = 0; i < 64; ++i) {
    float wv = w2[i * 64 + j];
#pragma unroll
    for (int n = 0; n < ENV; ++n) o[n] += hs[n][i] * wv;
  }
#pragma unroll
  for (int n = 0; n < ENV; ++n) enc[(bv0 + n) * 64 + j] = fmaxf(o[n], 0.f);
}

// ---- t = einsum('bvf,hfg->bhvg') + score projections, 8 nodes/block, XCD-pinned ----
#define TNV 8
__global__ void t_kernel(const float* __restrict__ enc, const float* __restrict__ gat_w,
                         const float* __restrict__ a1, const float* __restrict__ a2,
                         float* __restrict__ t, float* __restrict__ s_self,
                         float* __restrict__ s_nbr) {
  int b = blockIdx.x & 7;
  int v0 = (blockIdx.x >> 3) * TNV;
  int bv0 = b * V + v0;
  int tid = threadIdx.x;  // 256
  int h = tid >> 6, g = tid & 63;
  __shared__ float es[TNV][64];
  for (int i = tid; i < TNV * 64; i += 256) es[i >> 6][i & 63] = enc[bv0 * 64 + i];
  __syncthreads();
  float acc[TNV];
#pragma unroll
  for (int n = 0; n < TNV; ++n) acc[n] = 0.f;
  const float* w = gat_w + h * 64 * 64 + g;
  for (int f = 0; f < 64; ++f) {
    float wf = w[f * 64];
#pragma unroll
    for (int n = 0; n < TNV; ++n) acc[n] += es[n][f] * wf;
  }
  float a1v = a1[h * 64 + g], a2v = a2[h * 64 + g];
#pragma unroll
  for (int n = 0; n < TNV; ++n) {
    t[((size_t)(b * H + h) * V + (v0 + n)) * 64 + g] = acc[n];
    float v1 = wave_sum(acc[n] * a1v);
    float v2 = wave_sum(acc[n] * a2v);
    if (g == 0) {
      s_self[(b * H + h) * V + (v0 + n)] = v1;
      s_nbr[(b * H + h) * V + (v0 + n)] = v2;
    }
  }
}

// ---- sparse GAT attention + head-mean + gate, XCD-pinned by batch ----
__global__ void gat_kernel(const float* __restrict__ enc_in, const float* __restrict__ t,
                           const float* __restrict__ s_self, const float* __restrict__ s_nbr,
                           const int* __restrict__ nbr, const int* __restrict__ deg,
                           const float* __restrict__ gate_w, const float* __restrict__ gate_u,
                           const float* __restrict__ gate_b, float* __restrict__ enc_out) {
  int b = blockIdx.x & 7;
  int v = blockIdx.x >> 3;
  int bv = b * V + v;
  int tid = threadIdx.x;
  int h = tid >> 6, lane = tid & 63;
  int dvv = deg[v];
  int wk = (lane < dvv) ? nbr[v * CAP + lane] : 0;
  float logit = -1e30f;
  if (lane < dvv) {
    float x = s_self[(b * H + h) * V + v] + s_nbr[(b * H + h) * V + wk];
    logit = (x > 0.f) ? x : 0.2f * x;  // leaky_relu 0.2
  }
  float m = wave_max(logit);
  float e = (lane < dvv) ? __expf(logit - m) : 0.f;
  float s = wave_sum(e);
  float coef = e / s;
  const float* tb = t + (size_t)(b * H + h) * (V * 64);
  float acc = 0.f;
  for (int k = 0; k < dvv; ++k) {
    float c = __shfl(coef, k);
    int w = __shfl(wk, k);
    acc += c * tb[w * 64 + lane];
  }
  __shared__ float hsum[4][64];
  __shared__ float nxts[64], encs[64];
  hsum[h][lane] = acc;
  __syncthreads();
  if (tid < 64) {
    float s4 = hsum[0][tid] + hsum[1][tid] + hsum[2][tid] + hsum[3][tid];
    nxts[tid] = fmaxf(0.25f * s4, 0.f);
    encs[tid] = enc_in[bv * 64 + tid];
  }
  __syncthreads();
  float part = 0.f;
  for (int f = h * 16; f < h * 16 + 16; ++f)
    part += nxts[f] * gate_w[f * 64 + lane] + encs[f] * gate_u[f * 64 + lane];
  __syncthreads();
  hsum[h][lane] = part;
  __syncthreads();
  if (tid < 64) {
    float zs = hsum[0][tid] + hsum[1][tid] + hsum[2][tid] + hsum[3][tid] + gate_b[tid];
    float z = 1.f / (1.f + __expf(-zs));
    enc_out[bv * 64 + tid] = z * nxts[tid] + (1.f - z) * encs[tid];
  }
}

// ---- decoder hidden (linear) + dual variable dv, 8 nodes/block, XCD-pinned ----
#define DNV 8
__global__ void dec_dual_kernel(const float* __restrict__ enc, const float* __restrict__ dw1,
                                const float* __restrict__ db1, const float* __restrict__ uw1,
                                const float* __restrict__ ub1, const float* __restrict__ uw2,
                                const float* __restrict__ ub2, float* __restrict__ hid,
                                float* __restrict__ dv) {
  int b = blockIdx.x & 7;
  int v0 = (blockIdx.x >> 3) * DNV;
  int bv0 = b * V + v0;
  int j = threadIdx.x;  // 64
  __shared__ float es[DNV][64];
#pragma unroll
  for (int n = 0; n < DNV; ++n) es[n][j] = enc[(bv0 + n) * 64 + j];
  __syncthreads();
  float hj[DNV], uj[DNV];
#pragma unroll
  for (int n = 0; n < DNV; ++n) { hj[n] = db1[j]; uj[n] = ub1[j]; }
  for (int f = 0; f < 64; ++f) {
    float a = dw1[f * 64 + j], c = uw1[f * 64 + j];
#pragma unroll
    for (int n = 0; n < DNV; ++n) {
      hj[n] += es[n][f] * a;
      uj[n] += es[n][f] * c;
    }
  }
  float w2v = uw2[j];
#pragma unroll
  for (int n = 0; n < DNV; ++n) {
    hid[(bv0 + n) * 64 + j] = hj[n];  // NO relu: decoder is linear
    float s = wave_sum(uj[n] * w2v);
    if (j == 0) dv[bv0 + n] = s + ub2[0];
  }
}

__global__ void transpose_w2(const float* __restrict__ w2, float* __restrict__ w2t) {
  int w = blockIdx.x, j = threadIdx.x;
  w2t[w * 64 + j] = w2[j * V + w];
}

// ---- flow weights: softmax over out-edges of pred^2, scattered DIRECTLY into
//      CSC-ordered per-batch edge array fwe; also row sum of fw^2; XCD-pinned ----
__global__ void fw_kernel(const float* __restrict__ hid, const float* __restrict__ w2t,
                          const float* __restrict__ b2, const int* __restrict__ nbr,
                          const int* __restrict__ deg, const int* __restrict__ csc_pos,
                          float* __restrict__ fwe, float* __restrict__ rssq) {
  int b = blockIdx.x & 7;
  int v = blockIdx.x >> 3;
  int bv = b * V + v;
  int lane = threadIdx.x;  // 64
  float hj = hid[bv * 64 + lane];
  int dvv = deg[v];
  float myp = -1e30f;
  for (int k = 0; k < dvv; ++k) {
    int w = nbr[v * CAP + k];  // wave-uniform
    float d = wave_sum(hj * w2t[w * 64 + lane]);
    float pp = d + b2[w];
    pp = pp * pp;
    if (lane == k) myp = pp;
  }
  float m = wave_max(myp);
  float e = (lane < dvv) ? __expf(myp - m) : 0.f;
  float s = wave_sum(e);
  float coef = e / s;
  if (lane < dvv) fwe[(size_t)b * MAXNNZ + csc_pos[v * CAP + lane]] = coef;
  float r = wave_sum(coef * coef);
  if (lane == 0) rssq[bv] = r;
}

// ---- flow iterations entirely in LDS (coalesced staging) + dual cost ----
__global__ __launch_bounds__(1024) void flow_dual_kernel(
    const float* __restrict__ fwe, const float* __restrict__ rssq,
    const unsigned short* __restrict__ c_src, const int* __restrict__ in_off,
    const float* __restrict__ dv, const float* __restrict__ demands,
    const int* __restrict__ nbr_out, const int* __restrict__ deg_out,
    float* __restrict__ partial) {
  int b = blockIdx.x;
  int v = threadIdx.x;  // 1024
  __shared__ float lfw[MAXNNZ];            // 80 KB
  __shared__ unsigned short lsrc[MAXNNZ];  // 40 KB
  __shared__ float oA[V], oB[V];           // 8 KB
  __shared__ float dvs[V];                 // 4 KB
  __shared__ float red[16];
  int nnz = in_off[V];
  if (nnz > MAXNNZ) nnz = MAXNNZ;
  const float* fwb = fwe + (size_t)b * MAXNNZ;
  for (int e = v; e < nnz; e += V) {  // fully coalesced staging
    lfw[e] = fwb[e];
    lsrc[e] = c_src[e];
  }
  float dem = demands[b * V + v];
  dvs[v] = dv[b * V + v];
  int o0 = in_off[v], o1 = in_off[v + 1];
  if (o1 > nnz) o1 = nnz;
  if (o0 > nnz) o0 = nnz;
  oA[v] = fmaxf(-dem, 0.f);  // o_1 = relu(-demand)
  __syncthreads();
  float* cur = oA;
  float* nxt = oB;
  for (int it = 0; it < 9; ++it) {
    float inflow = 0.f;
    for (int e = o0; e < o1; ++e) inflow += lfw[e] * cur[lsrc[e]];
    nxt[v] = fmaxf(inflow - dem, 0.f);
    __syncthreads();
    float* tmp = cur; cur = nxt; nxt = tmp;
  }
  float o10 = cur[v];
  float local = o10 * o10 * rssq[b * V + v];  // flow_cost contribution
  float dvv = dvs[v];
  int dout = deg_out[v];
  float acc = 0.f;
  for (int k = 0; k < dout; ++k) {
    float diff = dvv - dvs[nbr_out[v * CAP + k]];
    if (diff > 0.f) acc += diff * diff;
  }
  local += 0.25f * acc + dvv * dem;
  local = wave_sum(local);
  if ((v & 63) == 0) red[v >> 6] = local;
  __syncthreads();
  if (v < 16) {
    float r = red[v];
    for (int o = 8; o > 0; o >>= 1) r += __shfl_xor(r, o, 16);
    if (v == 0) partial[b] = r;
  }
}

__global__ void final_kernel(const float* __restrict__ partial, float* __restrict__ out) {
  if (threadIdx.x == 0) {
    float s = 0.f;
    for (int b = 0; b < B; ++b) s += partial[b];
    out[0] = s * (1.0f / B);
  }
}

extern "C" void kernel_launch(void* const* d_in, const int* in_sizes, int n_in,
                              void* d_out, int out_size, void* d_ws, size_t ws_size,
                              hipStream_t stream) {
  const float* demands = (const float*)d_in[0];
  const float* emb     = (const float*)d_in[1];
  const float* adj     = (const float*)d_in[2];
  const float* enc_w1  = (const float*)d_in[3];
  const float* enc_b1  = (const float*)d_in[4];
  const float* enc_w2  = (const float*)d_in[5];
  const float* enc_b2  = (const float*)d_in[6];
  const float* gat_w   = (const float*)d_in[7];
  const float* gat_a1  = (const float*)d_in[8];
  const float* gat_a2  = (const float*)d_in[9];
  const float* gate_w  = (const float*)d_in[10];
  const float* gate_u  = (const float*)d_in[11];
  const float* gate_b  = (const float*)d_in[12];
  const float* dec_w1  = (const float*)d_in[13];
  const float* dec_b1  = (const float*)d_in[14];
  const float* dec_w2  = (const float*)d_in[15];
  const float* dec_b2  = (const float*)d_in[16];
  const float* dual_w1 = (const float*)d_in[17];
  const float* dual_b1 = (const float*)d_in[18];
  const float* dual_w2 = (const float*)d_in[19];
  const float* dual_b2 = (const float*)d_in[20];

  char* p = (char*)d_ws;
  auto alloc = [&](size_t n) { void* r = (void*)p; p += (n + 255) & ~(size_t)255; return r; };
  int* nbr_out   = (int*)alloc((size_t)V * CAP * 4);
  int* deg_out   = (int*)alloc((size_t)V * 4);
  int* deg_in    = (int*)alloc((size_t)V * 4);
  int* in_off    = (int*)alloc((size_t)(V + 1) * 4);
  unsigned short* c_src = (unsigned short*)alloc((size_t)MAXNNZ * 2);
  unsigned short* c_w   = (unsigned short*)alloc((size_t)MAXNNZ * 2);
  int* csc_pos   = (int*)alloc((size_t)V * CAP * 4);
  float* fwe     = (float*)alloc((size_t)B * MAXNNZ * 4);
  float* w2t     = (float*)alloc((size_t)HIDN * V * 4);
  float* encA    = (float*)alloc((size_t)B * V * 64 * 4);
  float* encB    = (float*)alloc((size_t)B * V * 64 * 4);
  float* t       = (float*)alloc((size_t)B * H * V * 64 * 4);
  float* s_self  = (float*)alloc((size_t)B * H * V * 4);
  float* s_nbr   = (float*)alloc((size_t)B * H * V * 4);
  float* hid     = (float*)alloc((size_t)B * V * 64 * 4);
  float* dv      = (float*)alloc((size_t)B * V * 4);
  float* rssq    = (float*)alloc((size_t)B * V * 4);
  float* partial = (float*)alloc((size_t)B * 4);

  build_csr<<<V, 64, 0, stream>>>(adj, nbr_out, deg_out);
  colcount_kernel<<<V / 64, 1024, 0, stream>>>(adj, deg_in);
  scan_kernel<<<1, V, 0, stream>>>(deg_in, in_off);
  build_csc2<<<V / 64, 1024, 0, stream>>>(adj, in_off, c_src, c_w);
  kkmap_kernel<<<(MAXNNZ + 255) / 256, 256, 0, stream>>>(c_src, c_w, nbr_out, in_off, csc_pos);
  enc_kernel<<<B * V / ENV, 64, 0, stream>>>(demands, emb, enc_w1, enc_b1, enc_w2, enc_b2, encA);
  float* cur = encA;
  float* nxt = encB;
  for (int l = 0; l < 2; ++l) {
    t_kernel<<<B * V / TNV, 256, 0, stream>>>(cur, gat_w, gat_a1, gat_a2, t, s_self, s_nbr);
    gat_kernel<<<B * V, 256, 0, stream>>>(cur, t, s_self, s_nbr, nbr_out, deg_out,
                                          gate_w, gate_u, gate_b, nxt);
    float* tmp = cur; cur = nxt; nxt = tmp;
  }
  transpose_w2<<<V, 64, 0, stream>>>(dec_w2, w2t);
  dec_dual_kernel<<<B * V / DNV, 64, 0, stream>>>(cur, dec_w1, dec_b1, dual_w1, dual_b1,
                                                  dual_w2, dual_b2, hid, dv);
  fw_kernel<<<B * V, 64, 0, stream>>>(hid, w2t, dec_b2, nbr_out, deg_out, csc_pos, fwe, rssq);
  flow_dual_kernel<<<B, 1024, 0, stream>>>(fwe, rssq, c_src, in_off, dv, demands,
                                           nbr_out, deg_out, partial);
  final_kernel<<<1, 64, 0, stream>>>(partial, (float*)d_out);
}